// Round 1
// baseline (4344.867 us; speedup 1.0000x reference)
//
#include <hip/hip_runtime.h>
#include <math.h>

constexpr int WID  = 320;
constexpr int HWc  = 320 * 320;        // 102400
constexpr int NIMG = 16;
constexpr int NSL  = 32;               // B*C slices for TV/DWT
constexpr int NTOT = NIMG * 2 * HWc;   // 3276800 floats per full array
constexpr float LAM_TV  = 0.005f;
constexpr float LAM_WAV = 0.005f;

__device__ __forceinline__ float softt(float v) {
    float a = fmaxf(fabsf(v) - LAM_WAV, 0.f);
    return copysignf(a, v);
}

// ---------------- centered 320-point FFT pass (rows or cols) ----------------
// SGN = -1 forward, +1 inverse. ortho scaling 1/sqrt(320) per pass.
// One wave per line; lane holds 5 elements. 320 = 5 (reg DFT) x 64 (lane FFT).
template<int SGN>
__global__ __launch_bounds__(256) void fft_pass(const float* __restrict__ in,
                                                float* __restrict__ out,
                                                int estride, int lstride) {
    const int lane = threadIdx.x & 63;
    const int wv   = threadIdx.x >> 6;
    const int L    = blockIdx.x * 4 + wv;        // 16*320 lines total
    const int img  = L / 320;
    const int l    = L - img * 320;
    const float* pre = in + img * (2 * HWc) + l * lstride;
    const float* pim = pre + HWc;

    float vr[5], vi[5];
    const float sgn_in = (lane & 1) ? -1.f : 1.f;   // (-1)^n, 64m is even
#pragma unroll
    for (int m = 0; m < 5; m++) {
        int n = lane + 64 * m;
        vr[m] = sgn_in * pre[n * estride];
        vi[m] = sgn_in * pim[n * estride];
    }

    // DFT-5 over m (exact constants)
    const float cw1 = 0.30901699437494745f, sw1 = 0.9510565162951535f;
    const float cw2 = -0.8090169943749475f, sw2 = 0.5877852522924731f;
    const float cwt[5] = {1.f, cw1, cw2, cw2, cw1};
    const float swt[5] = {0.f, sw1, sw2, -sw2, -sw1};
    float Cr[5], Ci[5];
    Cr[0] = vr[0] + vr[1] + vr[2] + vr[3] + vr[4];
    Ci[0] = vi[0] + vi[1] + vi[2] + vi[3] + vi[4];
#pragma unroll
    for (int k = 1; k < 5; k++) {
        float ar = vr[0], ai = vi[0];
#pragma unroll
        for (int m = 1; m < 5; m++) {
            int j = (m * k) % 5;
            float wr_ = cwt[j], wi_ = (float)SGN * swt[j];
            ar += vr[m] * wr_ - vi[m] * wi_;
            ai += vr[m] * wi_ + vi[m] * wr_;
        }
        Cr[k] = ar; Ci[k] = ai;
    }

    // twiddle W_320^{lane*k}
    float ts, tc;
    __sincosf((float)SGN * 6.283185307179586f * (float)lane / 320.f, &ts, &tc);
    float twr = 1.f, twi = 0.f;
#pragma unroll
    for (int k = 1; k < 5; k++) {
        float nr = twr * tc - twi * ts;
        twi = twr * ts + twi * tc;
        twr = nr;
        float r = Cr[k] * twr - Ci[k] * twi;
        Ci[k]   = Cr[k] * twi + Ci[k] * twr;
        Cr[k]   = r;
    }

    // per-stage lane-FFT twiddles (k2-independent)
    float stc[6], sts[6];
#pragma unroll
    for (int s = 0; s < 6; s++) {
        int h = 32 >> s;
        int j = lane & (h - 1);
        float ang = (float)SGN * 3.14159265358979323f * (float)j / (float)h;
        __sincosf(ang, &sts[s], &stc[s]);
    }

    // 6-stage radix-2 DIF across 64 lanes (Gentleman-Sande, bitrev output)
#pragma unroll
    for (int s = 0; s < 6; s++) {
        int h = 32 >> s;
        bool up = (lane & h) != 0;
#pragma unroll
        for (int k = 0; k < 5; k++) {
            float orr = __shfl_xor(Cr[k], h);
            float oii = __shfl_xor(Ci[k], h);
            if (up) {
                float dr = orr - Cr[k], di = oii - Ci[k];
                Cr[k] = dr * stc[s] - di * sts[s];
                Ci[k] = dr * sts[s] + di * stc[s];
            } else {
                Cr[k] += orr;
                Ci[k] += oii;
            }
        }
    }

    const int k1 = (int)(__brev((unsigned)lane) >> 26);   // bitrev6
    float* qre = out + img * (2 * HWc) + l * lstride;
    float* qim = qre + HWc;
    const float scale = 0.05590169943749474f;  // 1/sqrt(320)
#pragma unroll
    for (int k = 0; k < 5; k++) {
        int kout = 5 * k1 + k;
        float s2 = (kout & 1) ? -scale : scale;  // (-1)^k * ortho scale
        qre[kout * estride] = s2 * Cr[k];
        qim[kout * estride] = s2 * Ci[k];
    }
}

// ---------------- elementwise kernels ----------------
__global__ __launch_bounds__(256) void dc_kernel(float* K, const float* __restrict__ y,
                                                 const float* __restrict__ mask) {
    int idx = blockIdx.x * 256 + threadIdx.x;
    if (idx >= NIMG * HWc) return;
    int img = idx / HWc;
    int q   = idx - img * HWc;
    float m = mask[idx];
    int b = img * (2 * HWc) + q;
    K[b]       = m * (m * K[b]       - y[b]);
    K[b + HWc] = m * (m * K[b + HWc] - y[b + HWc]);
}

__global__ __launch_bounds__(256) void sub_kernel(const float* __restrict__ a,
                                                  const float* __restrict__ b,
                                                  float* __restrict__ o) {
    int idx = blockIdx.x * 256 + threadIdx.x;
    if (idx >= NTOT) return;
    o[idx] = a[idx] - b[idx];
}

__global__ __launch_bounds__(256) void copy_kernel(const float* __restrict__ a,
                                                   float* __restrict__ o) {
    int idx = blockIdx.x * 256 + threadIdx.x;
    if (idx >= NTOT) return;
    o[idx] = a[idx];
}

__global__ __launch_bounds__(256) void fista_update(const float* __restrict__ xn,
                                                    float* x, float* z, float beta) {
    int idx = blockIdx.x * 256 + threadIdx.x;
    if (idx >= NTOT) return;
    float v  = xn[idx];
    float xo = x[idx];
    z[idx] = v + beta * (v - xo);
    x[idx] = v;
}

// ---------------- TV prox ----------------
// first dual iter: p = proj(tau * grad(zs))   (p starts at 0)
__global__ __launch_bounds__(256) void tv_p_first(const float* __restrict__ zs,
                                                  float* __restrict__ P) {
    int idx = blockIdx.x * 256 + threadIdx.x;
    if (idx >= NSL * HWc) return;
    int s = idx / HWc;
    int pix = idx - s * HWc;
    int i = pix / WID, j = pix - i * WID;
    const float* u = zs + s * HWc;
    float uc = u[pix];
    float gx = (j < WID - 1) ? u[pix + 1]   - uc : 0.f;
    float gy = (i < WID - 1) ? u[pix + WID] - uc : 0.f;
    float px = 0.25f * gx, py = 0.25f * gy;
    float nrm = sqrtf(px * px + py * py + 1e-8f);
    float d = fmaxf(nrm, 1.f);
    P[s * 2 * HWc + pix]       = px / d;
    P[s * 2 * HWc + HWc + pix] = py / d;
}

// u = zs - lam * div(p)
__global__ __launch_bounds__(256) void tv_u(const float* __restrict__ zs,
                                            const float* __restrict__ P,
                                            float* __restrict__ U) {
    int idx = blockIdx.x * 256 + threadIdx.x;
    if (idx >= NSL * HWc) return;
    int s = idx / HWc;
    int pix = idx - s * HWc;
    int i = pix / WID, j = pix - i * WID;
    const float* px = P + s * 2 * HWc;
    const float* py = px + HWc;
    float divx, divy;
    if (j == 0)            divx = px[pix];
    else if (j == WID - 1) divx = -px[pix - 1];
    else                   divx = px[pix] - px[pix - 1];
    if (i == 0)            divy = py[pix];
    else if (i == WID - 1) divy = -py[pix - WID];
    else                   divy = py[pix] - py[pix - WID];
    U[s * HWc + pix] = zs[s * HWc + pix] - LAM_TV * (divx + divy);
}

// p = proj(p + tau * grad(u))   (pointwise in p -> in-place safe)
__global__ __launch_bounds__(256) void tv_p(const float* __restrict__ U,
                                            float* __restrict__ P) {
    int idx = blockIdx.x * 256 + threadIdx.x;
    if (idx >= NSL * HWc) return;
    int s = idx / HWc;
    int pix = idx - s * HWc;
    int i = pix / WID, j = pix - i * WID;
    const float* u = U + s * HWc;
    float uc = u[pix];
    float gx = (j < WID - 1) ? u[pix + 1]   - uc : 0.f;
    float gy = (i < WID - 1) ? u[pix + WID] - uc : 0.f;
    float px = P[s * 2 * HWc + pix]       + 0.25f * gx;
    float py = P[s * 2 * HWc + HWc + pix] + 0.25f * gy;
    float nrm = sqrtf(px * px + py * py + 1e-8f);
    float d = fmaxf(nrm, 1.f);
    P[s * 2 * HWc + pix]       = px / d;
    P[s * 2 * HWc + HWc + pix] = py / d;
}

// ---------------- Haar DWT (quadrant packed, stride 320) ----------------
__global__ __launch_bounds__(256) void dwt_fwd(const float* __restrict__ in,
                                               float* __restrict__ out, int n) {
    int half = n >> 1;
    int per = half * half;
    int idx = blockIdx.x * 256 + threadIdx.x;
    if (idx >= NSL * per) return;
    int s = idx / per;
    int r = idx - s * per;
    int i = r / half, j = r - i * half;
    const float* pin = in + s * HWc;
    float* pout = out + s * HWc;
    int r0 = (2 * i) * WID + 2 * j;
    float a = pin[r0], b = pin[r0 + 1], c = pin[r0 + WID], d = pin[r0 + WID + 1];
    float ll = (a + b + c + d) * 0.5f;
    float lh = (a + b - c - d) * 0.5f;
    float hl = (a - b + c - d) * 0.5f;
    float hh = (a - b - c + d) * 0.5f;
    pout[i * WID + j]                     = ll;
    pout[(i + half) * WID + j]            = softt(lh);
    pout[i * WID + (j + half)]            = softt(hl);
    pout[(i + half) * WID + (j + half)]   = softt(hh);
}

__global__ __launch_bounds__(256) void dwt_inv(const float* __restrict__ in,
                                               float* __restrict__ out, int n) {
    int half = n >> 1;
    int per = half * half;
    int idx = blockIdx.x * 256 + threadIdx.x;
    if (idx >= NSL * per) return;
    int s = idx / per;
    int r = idx - s * per;
    int i = r / half, j = r - i * half;
    const float* pin = in + s * HWc;
    float* pout = out + s * HWc;
    float ll = pin[i * WID + j];
    float lh = pin[(i + half) * WID + j];
    float hl = pin[i * WID + (j + half)];
    float hh = pin[(i + half) * WID + (j + half)];
    int r0 = (2 * i) * WID + 2 * j;
    pout[r0]           = (ll + lh + hl + hh) * 0.5f;
    pout[r0 + 1]       = (ll + lh - hl - hh) * 0.5f;
    pout[r0 + WID]     = (ll - lh + hl - hh) * 0.5f;
    pout[r0 + WID + 1] = (ll - lh - hl + hh) * 0.5f;
}

// ---------------- host orchestration ----------------
extern "C" void kernel_launch(void* const* d_in, const int* in_sizes, int n_in,
                              void* d_out, int out_size, void* d_ws, size_t ws_size,
                              hipStream_t stream) {
    const float* y    = (const float*)d_in[0];
    const float* mask = (const float*)d_in[1];
    float* x = (float*)d_out;

    float* ws = (float*)d_ws;
    float* z  = ws;                 // NTOT
    float* t1 = ws + (size_t)NTOT;  // NTOT
    float* t2 = ws + 2 * (size_t)NTOT;
    float* u  = ws + 3 * (size_t)NTOT;
    float* P  = ws + 4 * (size_t)NTOT;  // 2*NTOT (32 slices x 2 comps)

    const int FFT_BLKS = (NIMG * 320) / 4;          // 1280
    const int EW_BLKS  = (NTOT + 255) / 256;        // 12800
    const int DC_BLKS  = (NIMG * HWc + 255) / 256;  // 6400
    const int TV_BLKS  = (NSL * HWc + 255) / 256;   // 12800
    auto dwt_blks = [](int n) { int h = n >> 1; return (NSL * h * h + 255) / 256; };

    // x0 = ifft2c(y); z = x0
    fft_pass<1><<<FFT_BLKS, 256, 0, stream>>>(y, t1, 1, WID);    // rows
    fft_pass<1><<<FFT_BLKS, 256, 0, stream>>>(t1, x, WID, 1);    // cols
    copy_kernel<<<EW_BLKS, 256, 0, stream>>>(x, z);

    float t = 1.f;
    for (int it = 0; it < 15; it++) {
        // k-space data consistency: g = ifft2c(mask*(mask*fft2c(z) - y))
        fft_pass<-1><<<FFT_BLKS, 256, 0, stream>>>(z, t1, 1, WID);
        fft_pass<-1><<<FFT_BLKS, 256, 0, stream>>>(t1, t2, WID, 1);
        dc_kernel<<<DC_BLKS, 256, 0, stream>>>(t2, y, mask);
        fft_pass<1><<<FFT_BLKS, 256, 0, stream>>>(t2, t1, 1, WID);
        fft_pass<1><<<FFT_BLKS, 256, 0, stream>>>(t1, t2, WID, 1);   // g
        sub_kernel<<<EW_BLKS, 256, 0, stream>>>(z, t2, t1);          // zs = z - g

        // TV prox (5 dual iterations)
        tv_p_first<<<TV_BLKS, 256, 0, stream>>>(t1, P);
        for (int k = 0; k < 4; k++) {
            tv_u<<<TV_BLKS, 256, 0, stream>>>(t1, P, u);
            tv_p<<<TV_BLKS, 256, 0, stream>>>(u, P);
        }
        tv_u<<<TV_BLKS, 256, 0, stream>>>(t1, P, u);   // u = x_tv

        // 3-level Haar + soft-threshold + inverse
        dwt_fwd<<<dwt_blks(320), 256, 0, stream>>>(u, t2, 320);
        dwt_fwd<<<dwt_blks(160), 256, 0, stream>>>(t2, t1, 160);
        dwt_fwd<<<dwt_blks(80),  256, 0, stream>>>(t1, t2, 80);
        dwt_inv<<<dwt_blks(80),  256, 0, stream>>>(t2, t1, 80);
        dwt_inv<<<dwt_blks(160), 256, 0, stream>>>(t1, t2, 160);
        dwt_inv<<<dwt_blks(320), 256, 0, stream>>>(t2, u, 320);      // u = x_new

        // FISTA momentum (t sequence is data-independent -> host side)
        float tn   = (1.f + sqrtf(1.f + 4.f * t * t)) * 0.5f;
        float beta = (t - 1.f) / tn;
        t = tn;
        fista_update<<<EW_BLKS, 256, 0, stream>>>(u, x, z, beta);
    }
    (void)in_sizes; (void)n_in; (void)out_size; (void)ws_size;
}

// Round 2
// 3519.719 us; speedup vs baseline: 1.2344x; 1.2344x over previous
//
#include <hip/hip_runtime.h>
#include <math.h>

constexpr int WID  = 320;
constexpr int HWc  = 320 * 320;        // 102400
constexpr int NIMG = 16;
constexpr int NSL  = 32;               // B*C slices for TV/DWT
constexpr int NTOT = NIMG * 2 * HWc;   // 3276800 floats per full array
constexpr float LAM_TV  = 0.005f;
constexpr float LAM_WAV = 0.005f;

__device__ __forceinline__ float softt(float v) {
    float a = fmaxf(fabsf(v) - LAM_WAV, 0.f);
    return copysignf(a, v);
}

// ---------------- centered 320-point FFT pass (rows or cols) ----------------
// SGN = -1 forward, +1 inverse. ortho scaling 1/sqrt(320) per pass.
// One wave per line; lane holds 5 elements. 320 = 5 (reg DFT) x 64 (lane FFT).
// EPI: 0 = plain store
//      1 = data-consistency store:  out = m*(m*val - y)   (aux1=y, aux2=mask)
//      2 = residual store:          out = z - val         (aux1=z)
//      3 = dual store:              out and out2 both get val (out2=z)
template<int SGN, int EPI>
__global__ __launch_bounds__(256) void fft_pass(const float* __restrict__ in,
                                                float* __restrict__ out,
                                                int estride, int lstride,
                                                const float* __restrict__ aux1,
                                                const float* __restrict__ aux2,
                                                float* __restrict__ out2) {
    const int lane = threadIdx.x & 63;
    const int wv   = threadIdx.x >> 6;
    const int L    = blockIdx.x * 4 + wv;        // 16*320 lines total
    const int img  = L / 320;
    const int l    = L - img * 320;
    const float* pre = in + img * (2 * HWc) + l * lstride;
    const float* pim = pre + HWc;

    float vr[5], vi[5];
    const float sgn_in = (lane & 1) ? -1.f : 1.f;   // (-1)^n, 64m is even
#pragma unroll
    for (int m = 0; m < 5; m++) {
        int n = lane + 64 * m;
        vr[m] = sgn_in * pre[n * estride];
        vi[m] = sgn_in * pim[n * estride];
    }

    // DFT-5 over m (exact constants)
    const float cw1 = 0.30901699437494745f, sw1 = 0.9510565162951535f;
    const float cw2 = -0.8090169943749475f, sw2 = 0.5877852522924731f;
    const float cwt[5] = {1.f, cw1, cw2, cw2, cw1};
    const float swt[5] = {0.f, sw1, sw2, -sw2, -sw1};
    float Cr[5], Ci[5];
    Cr[0] = vr[0] + vr[1] + vr[2] + vr[3] + vr[4];
    Ci[0] = vi[0] + vi[1] + vi[2] + vi[3] + vi[4];
#pragma unroll
    for (int k = 1; k < 5; k++) {
        float ar = vr[0], ai = vi[0];
#pragma unroll
        for (int m = 1; m < 5; m++) {
            int j = (m * k) % 5;
            float wr_ = cwt[j], wi_ = (float)SGN * swt[j];
            ar += vr[m] * wr_ - vi[m] * wi_;
            ai += vr[m] * wi_ + vi[m] * wr_;
        }
        Cr[k] = ar; Ci[k] = ai;
    }

    // twiddle W_320^{lane*k}
    float ts, tc;
    __sincosf((float)SGN * 6.283185307179586f * (float)lane / 320.f, &ts, &tc);
    float twr = 1.f, twi = 0.f;
#pragma unroll
    for (int k = 1; k < 5; k++) {
        float nr = twr * tc - twi * ts;
        twi = twr * ts + twi * tc;
        twr = nr;
        float r = Cr[k] * twr - Ci[k] * twi;
        Ci[k]   = Cr[k] * twi + Ci[k] * twr;
        Cr[k]   = r;
    }

    // per-stage lane-FFT twiddles (k2-independent)
    float stc[6], sts[6];
#pragma unroll
    for (int s = 0; s < 6; s++) {
        int h = 32 >> s;
        int j = lane & (h - 1);
        float ang = (float)SGN * 3.14159265358979323f * (float)j / (float)h;
        __sincosf(ang, &sts[s], &stc[s]);
    }

    // 6-stage radix-2 DIF across 64 lanes (Gentleman-Sande, bitrev output)
#pragma unroll
    for (int s = 0; s < 6; s++) {
        int h = 32 >> s;
        bool up = (lane & h) != 0;
#pragma unroll
        for (int k = 0; k < 5; k++) {
            float orr = __shfl_xor(Cr[k], h);
            float oii = __shfl_xor(Ci[k], h);
            if (up) {
                float dr = orr - Cr[k], di = oii - Ci[k];
                Cr[k] = dr * stc[s] - di * sts[s];
                Ci[k] = dr * sts[s] + di * stc[s];
            } else {
                Cr[k] += orr;
                Ci[k] += oii;
            }
        }
    }

    const int k1 = (int)(__brev((unsigned)lane) >> 26);   // bitrev6
    float* qre = out + img * (2 * HWc) + l * lstride;
    float* qim = qre + HWc;
    const float scale = 0.05590169943749474f;  // 1/sqrt(320)
#pragma unroll
    for (int k = 0; k < 5; k++) {
        int kout = 5 * k1 + k;
        float s2 = (kout & 1) ? -scale : scale;  // (-1)^k * ortho scale
        float re = s2 * Cr[k];
        float im = s2 * Ci[k];
        const int idxs = kout * estride + l * lstride;  // within-slice pixel idx
        if (EPI == 1) {
            float m = aux2[img * HWc + idxs];
            re = m * (m * re - aux1[img * 2 * HWc + idxs]);
            im = m * (m * im - aux1[img * 2 * HWc + HWc + idxs]);
        }
        if (EPI == 2) {
            re = aux1[img * 2 * HWc + idxs] - re;
            im = aux1[img * 2 * HWc + HWc + idxs] - im;
        }
        qre[kout * estride] = re;
        qim[kout * estride] = im;
        if (EPI == 3) {
            out2[img * 2 * HWc + idxs]       = re;
            out2[img * 2 * HWc + HWc + idxs] = im;
        }
    }
}

// ---------------- fused TV prox (all 5 dual iterations in one kernel) -------
// Tile 32x32 with halo 5 -> 42x42 LDS region. Exactness by shrinkage:
// u5 correct on [5,37)^2 = interior tile. Boundary rules keyed on GLOBAL
// coords so image-edge tiles are exact; out-of-image halo garbage never
// crosses into in-image cells (boundary branches cut the dependency).
constexpr int TT  = 32;
constexpr int TR  = 5;
constexpr int TRW = TT + 2 * TR;        // 42
constexpr int TCELLS = TRW * TRW;       // 1764

__device__ __forceinline__ float tv_div(const float* s_px, const float* s_py,
                                        int c, int gi, int gj, int li, int lj) {
    int cm1 = (lj > 0) ? c - 1 : c;
    int cmw = (li > 0) ? c - TRW : c;
    float divx, divy;
    if (gj <= 0)            divx = s_px[c];
    else if (gj >= WID - 1) divx = -s_px[cm1];
    else                    divx = s_px[c] - s_px[cm1];
    if (gi <= 0)            divy = s_py[c];
    else if (gi >= WID - 1) divy = -s_py[cmw];
    else                    divy = s_py[c] - s_py[cmw];
    return divx + divy;
}

__global__ __launch_bounds__(256) void tv_fused(const float* __restrict__ zs,
                                                float* __restrict__ out) {
    __shared__ float s_zs[TCELLS], s_u[TCELLS], s_px[TCELLS], s_py[TCELLS];
    const int tid = threadIdx.x;
    const int tps = (WID / TT) * (WID / TT);   // 100 tiles per slice
    const int sl  = blockIdx.x / tps;
    const int t   = blockIdx.x - sl * tps;
    const int ti  = (t / (WID / TT)) * TT - TR;   // global row of local 0
    const int tj  = (t % (WID / TT)) * TT - TR;
    const float* g = zs + sl * HWc;

    for (int c = tid; c < TCELLS; c += 256) {
        int li = c / TRW, lj = c - li * TRW;
        int gi = ti + li, gj = tj + lj;
        bool in = (gi >= 0 && gi < WID && gj >= 0 && gj < WID);
        s_zs[c] = in ? g[gi * WID + gj] : 0.f;
        s_px[c] = 0.f;
        s_py[c] = 0.f;
    }
    __syncthreads();

    for (int it = 0; it < 5; it++) {
        // u = zs - lam*div(p)
        for (int c = tid; c < TCELLS; c += 256) {
            int li = c / TRW, lj = c - li * TRW;
            int gi = ti + li, gj = tj + lj;
            s_u[c] = s_zs[c] - LAM_TV * tv_div(s_px, s_py, c, gi, gj, li, lj);
        }
        __syncthreads();
        // p = proj(p + tau*grad(u))   (pointwise in p -> in-place safe)
        for (int c = tid; c < TCELLS; c += 256) {
            int li = c / TRW, lj = c - li * TRW;
            int gi = ti + li, gj = tj + lj;
            int cp1 = (lj < TRW - 1) ? c + 1 : c;
            int cpw = (li < TRW - 1) ? c + TRW : c;
            float gx = (gj < WID - 1) ? s_u[cp1] - s_u[c] : 0.f;
            float gy = (gi < WID - 1) ? s_u[cpw] - s_u[c] : 0.f;
            float px = s_px[c] + 0.25f * gx;
            float py = s_py[c] + 0.25f * gy;
            float nrm = sqrtf(px * px + py * py + 1e-8f);
            float d = fmaxf(nrm, 1.f);
            s_px[c] = px / d;
            s_py[c] = py / d;
        }
        __syncthreads();
    }

    // final: out = zs - lam*div(p) on interior tile only
    float* o = out + sl * HWc;
    for (int c = tid; c < TT * TT; c += 256) {
        int li = c / TT + TR, lj = (c % TT) + TR;
        int cc = li * TRW + lj;
        int gi = ti + li, gj = tj + lj;
        o[gi * WID + gj] = s_zs[cc] - LAM_TV * tv_div(s_px, s_py, cc, gi, gj, li, lj);
    }
}

// ---------------- fused 3-level Haar + soft-threshold + inverse + FISTA -----
// The whole forward+threshold+inverse chain is local within each 8x8 pixel
// block (2x2 -> 4x4 -> 8x8 support). One thread per block, all in registers.
template<int N>
__device__ __forceinline__ void haar_fwd8(const float* in, float* out) {
    const int h = N / 2;
#pragma unroll
    for (int i = 0; i < h; i++)
#pragma unroll
        for (int j = 0; j < h; j++) {
            float a = in[(2 * i) * 8 + 2 * j],     b = in[(2 * i) * 8 + 2 * j + 1];
            float c = in[(2 * i + 1) * 8 + 2 * j], d = in[(2 * i + 1) * 8 + 2 * j + 1];
            out[i * 8 + j]             = (a + b + c + d) * 0.5f;
            out[(i + h) * 8 + j]       = softt((a + b - c - d) * 0.5f);
            out[i * 8 + j + h]         = softt((a - b + c - d) * 0.5f);
            out[(i + h) * 8 + j + h]   = softt((a - b - c + d) * 0.5f);
        }
}

template<int N>
__device__ __forceinline__ void haar_inv8(const float* in, float* out) {
    const int h = N / 2;
#pragma unroll
    for (int i = 0; i < h; i++)
#pragma unroll
        for (int j = 0; j < h; j++) {
            float ll = in[i * 8 + j],       lh = in[(i + h) * 8 + j];
            float hl = in[i * 8 + j + h],   hh = in[(i + h) * 8 + j + h];
            out[(2 * i) * 8 + 2 * j]         = (ll + lh + hl + hh) * 0.5f;
            out[(2 * i) * 8 + 2 * j + 1]     = (ll + lh - hl - hh) * 0.5f;
            out[(2 * i + 1) * 8 + 2 * j]     = (ll - lh + hl - hh) * 0.5f;
            out[(2 * i + 1) * 8 + 2 * j + 1] = (ll - lh - hl + hh) * 0.5f;
        }
}

__global__ __launch_bounds__(256) void wav_fista(const float* __restrict__ u,
                                                 float* __restrict__ x,
                                                 float* __restrict__ z,
                                                 float beta) {
    const int idx = blockIdx.x * 256 + threadIdx.x;   // one per 8x8 block
    const int nb  = WID / 8;       // 40
    const int per = nb * nb;       // 1600
    const int sl  = idx / per;
    const int b   = idx - sl * per;
    const int bi  = (b / nb) * 8, bj = (b % nb) * 8;
    const size_t base = (size_t)sl * HWc + (size_t)bi * WID + bj;

    float v[64], w[64];
    const float* pu = u + base;
#pragma unroll
    for (int r = 0; r < 8; r++) {
        float4 lo = *(const float4*)(pu + r * WID);
        float4 hi = *(const float4*)(pu + r * WID + 4);
        v[r * 8 + 0] = lo.x; v[r * 8 + 1] = lo.y; v[r * 8 + 2] = lo.z; v[r * 8 + 3] = lo.w;
        v[r * 8 + 4] = hi.x; v[r * 8 + 5] = hi.y; v[r * 8 + 6] = hi.z; v[r * 8 + 7] = hi.w;
    }

    haar_fwd8<8>(v, w);   // L1: v -> w (ll 4x4 + thresholded details)
    haar_fwd8<4>(w, v);   // L2: w's 4x4 ll -> v's top-left 4x4
    {                     // L3 in place on v's 2x2 (threshold details only)
        float a = v[0], b2 = v[1], c = v[8], d = v[9];
        v[0] = (a + b2 + c + d) * 0.5f;
        v[8] = softt((a + b2 - c - d) * 0.5f);
        v[1] = softt((a - b2 + c - d) * 0.5f);
        v[9] = softt((a - b2 - c + d) * 0.5f);
    }
    {                     // I3: reconstruct ll2' into v's 2x2
        float ll = v[0], lh = v[8], hl = v[1], hh = v[9];
        v[0] = (ll + lh + hl + hh) * 0.5f;
        v[1] = (ll + lh - hl - hh) * 0.5f;
        v[8] = (ll - lh + hl - hh) * 0.5f;
        v[9] = (ll - lh - hl + hh) * 0.5f;
    }
    haar_inv8<4>(v, w);   // I2: ll2' + d2 -> ll1' into w's top-left 4x4
    haar_inv8<8>(w, v);   // I1: ll1' + d1 -> x_new 8x8 into v

    // FISTA: z = xn + beta*(xn - x_old); x = xn
    float* px = x + base;
    float* pz = z + base;
#pragma unroll
    for (int r = 0; r < 8; r++) {
        float4 xo_lo = *(const float4*)(px + r * WID);
        float4 xo_hi = *(const float4*)(px + r * WID + 4);
        float4 nlo, nhi, zlo, zhi;
        nlo.x = v[r * 8 + 0]; nlo.y = v[r * 8 + 1]; nlo.z = v[r * 8 + 2]; nlo.w = v[r * 8 + 3];
        nhi.x = v[r * 8 + 4]; nhi.y = v[r * 8 + 5]; nhi.z = v[r * 8 + 6]; nhi.w = v[r * 8 + 7];
        zlo.x = nlo.x + beta * (nlo.x - xo_lo.x);
        zlo.y = nlo.y + beta * (nlo.y - xo_lo.y);
        zlo.z = nlo.z + beta * (nlo.z - xo_lo.z);
        zlo.w = nlo.w + beta * (nlo.w - xo_lo.w);
        zhi.x = nhi.x + beta * (nhi.x - xo_hi.x);
        zhi.y = nhi.y + beta * (nhi.y - xo_hi.y);
        zhi.z = nhi.z + beta * (nhi.z - xo_hi.z);
        zhi.w = nhi.w + beta * (nhi.w - xo_hi.w);
        *(float4*)(px + r * WID)     = nlo;
        *(float4*)(px + r * WID + 4) = nhi;
        *(float4*)(pz + r * WID)     = zlo;
        *(float4*)(pz + r * WID + 4) = zhi;
    }
}

// ---------------- host orchestration ----------------
extern "C" void kernel_launch(void* const* d_in, const int* in_sizes, int n_in,
                              void* d_out, int out_size, void* d_ws, size_t ws_size,
                              hipStream_t stream) {
    const float* y    = (const float*)d_in[0];
    const float* mask = (const float*)d_in[1];
    float* x = (float*)d_out;

    float* ws = (float*)d_ws;
    float* z  = ws;                       // NTOT
    float* t1 = ws + (size_t)NTOT;        // NTOT
    float* t2 = ws + 2 * (size_t)NTOT;    // NTOT

    const int FFT_BLKS = (NIMG * 320) / 4;   // 1280
    const int TV_BLKS  = NSL * 100;          // 3200
    const int WV_BLKS  = (NSL * 1600) / 256; // 200

    // x0 = ifft2c(y); z = x0  (col pass dual-stores x and z)
    fft_pass<1, 0><<<FFT_BLKS, 256, 0, stream>>>(y, t1, 1, WID, nullptr, nullptr, nullptr);
    fft_pass<1, 3><<<FFT_BLKS, 256, 0, stream>>>(t1, x, WID, 1, nullptr, nullptr, z);

    float t = 1.f;
    for (int it = 0; it < 15; it++) {
        // k-space: K = fft2c(z); K = m*(m*K - y) fused into col-pass store
        fft_pass<-1, 0><<<FFT_BLKS, 256, 0, stream>>>(z, t1, 1, WID, nullptr, nullptr, nullptr);
        fft_pass<-1, 1><<<FFT_BLKS, 256, 0, stream>>>(t1, t2, WID, 1, y, mask, nullptr);
        // g = ifft2c(K); zs = z - g fused into col-pass store
        fft_pass<1, 0><<<FFT_BLKS, 256, 0, stream>>>(t2, t1, 1, WID, nullptr, nullptr, nullptr);
        fft_pass<1, 2><<<FFT_BLKS, 256, 0, stream>>>(t1, t2, WID, 1, z, nullptr, nullptr);

        // TV prox: 5 dual iterations in one kernel
        tv_fused<<<TV_BLKS, 256, 0, stream>>>(t2, t1);

        // 3-level wavelet shrinkage + FISTA momentum in one kernel
        float tn   = (1.f + sqrtf(1.f + 4.f * t * t)) * 0.5f;
        float beta = (t - 1.f) / tn;
        t = tn;
        wav_fista<<<WV_BLKS, 256, 0, stream>>>(t1, x, z, beta);
    }
    (void)in_sizes; (void)n_in; (void)out_size; (void)ws_size;
}

// Round 3
// 1967.202 us; speedup vs baseline: 2.2087x; 1.7892x over previous
//
#include <hip/hip_runtime.h>
#include <math.h>

constexpr int WID  = 320;
constexpr int HWc  = 320 * 320;        // 102400
constexpr int NIMG = 16;
constexpr int NSL  = 32;               // B*C slices for TV/DWT
constexpr int NTOT = NIMG * 2 * HWc;   // 3276800 floats per full array
constexpr float LAM_TV  = 0.005f;
constexpr float LAM_WAV = 0.005f;

__device__ __forceinline__ float softt(float v) {
    float a = fmaxf(fabsf(v) - LAM_WAV, 0.f);
    return copysignf(a, v);
}

// ================= 320-point FFT core (shared by row & col kernels) =========
// 320 = 5 (register DFT) x 64 (lane FFT via shfl_xor). Centered transform via
// (-1)^n modulation at load and (-1)^k at store (N even; handled by callers).
struct Tw { float tc, ts; float stc[6], sts[6]; };

template<int SGN>
__device__ __forceinline__ Tw make_tw(int lane) {
    Tw tw;
    __sincosf((float)SGN * 6.283185307179586f * (float)lane / 320.f, &tw.ts, &tw.tc);
#pragma unroll
    for (int s = 0; s < 6; s++) {
        int h = 32 >> s;
        int j = lane & (h - 1);
        float ang = (float)SGN * 3.14159265358979323f * (float)j / (float)h;
        __sincosf(ang, &tw.sts[s], &tw.stc[s]);
    }
    return tw;
}

// in: vr/vi hold elements n = lane + 64m in slot m (already sign-modulated).
// out: Cr/Ci hold X[5*bitrev6(lane) + k] in slot k (unscaled).
template<int SGN>
__device__ __forceinline__ void fft320_core(const float (&vr)[5], const float (&vi)[5],
                                            float (&Cr)[5], float (&Ci)[5],
                                            const Tw& tw, int lane) {
    const float cw1 = 0.30901699437494745f, sw1 = 0.9510565162951535f;
    const float cw2 = -0.8090169943749475f, sw2 = 0.5877852522924731f;
    const float cwt[5] = {1.f, cw1, cw2, cw2, cw1};
    const float swt[5] = {0.f, sw1, sw2, -sw2, -sw1};
    Cr[0] = vr[0] + vr[1] + vr[2] + vr[3] + vr[4];
    Ci[0] = vi[0] + vi[1] + vi[2] + vi[3] + vi[4];
#pragma unroll
    for (int k = 1; k < 5; k++) {
        float ar = vr[0], ai = vi[0];
#pragma unroll
        for (int m = 1; m < 5; m++) {
            int j = (m * k) % 5;
            float wr_ = cwt[j], wi_ = (float)SGN * swt[j];
            ar += vr[m] * wr_ - vi[m] * wi_;
            ai += vr[m] * wi_ + vi[m] * wr_;
        }
        Cr[k] = ar; Ci[k] = ai;
    }
    // twiddle W_320^{lane*k}
    float twr = 1.f, twi = 0.f;
#pragma unroll
    for (int k = 1; k < 5; k++) {
        float nr = twr * tw.tc - twi * tw.ts;
        twi = twr * tw.ts + twi * tw.tc;
        twr = nr;
        float r = Cr[k] * twr - Ci[k] * twi;
        Ci[k]   = Cr[k] * twi + Ci[k] * twr;
        Cr[k]   = r;
    }
    // 6-stage radix-2 DIF across 64 lanes
#pragma unroll
    for (int s = 0; s < 6; s++) {
        int h = 32 >> s;
        bool up = (lane & h) != 0;
#pragma unroll
        for (int k = 0; k < 5; k++) {
            float orr = __shfl_xor(Cr[k], h);
            float oii = __shfl_xor(Ci[k], h);
            if (up) {
                float dr = orr - Cr[k], di = oii - Ci[k];
                Cr[k] = dr * tw.stc[s] - di * tw.sts[s];
                Ci[k] = dr * tw.sts[s] + di * tw.stc[s];
            } else {
                Cr[k] += orr;
                Ci[k] += oii;
            }
        }
    }
}

// ---------------- row FFT pass (coalesced; lines are contiguous rows) -------
// EPI: 0 = plain store
//      2 = residual store: out = aux1 - val   (aux1 = z)
//      3 = dual store:     out and out2 both get val
template<int SGN, int EPI>
__global__ __launch_bounds__(256) void fft_row(const float* __restrict__ in,
                                               float* __restrict__ out,
                                               const float* __restrict__ aux1,
                                               float* __restrict__ out2) {
    const int lane = threadIdx.x & 63;
    const int wv   = threadIdx.x >> 6;
    const int L    = blockIdx.x * 4 + wv;
    const int img  = L / 320;
    const int l    = L - img * 320;
    const float* pre = in + (size_t)img * 2 * HWc + (size_t)l * WID;
    const float* pim = pre + HWc;

    float vr[5], vi[5];
    const float sgn_in = (lane & 1) ? -1.f : 1.f;
#pragma unroll
    for (int m = 0; m < 5; m++) {
        int n = lane + 64 * m;
        vr[m] = sgn_in * pre[n];
        vi[m] = sgn_in * pim[n];
    }
    Tw tw = make_tw<SGN>(lane);
    float Cr[5], Ci[5];
    fft320_core<SGN>(vr, vi, Cr, Ci, tw, lane);

    const int k1 = (int)(__brev((unsigned)lane) >> 26);
    float* qre = out + (size_t)img * 2 * HWc + (size_t)l * WID;
    float* qim = qre + HWc;
    const float scale = 0.05590169943749474f;  // 1/sqrt(320)
#pragma unroll
    for (int k = 0; k < 5; k++) {
        int kout = 5 * k1 + k;
        float s2 = (kout & 1) ? -scale : scale;
        float re = s2 * Cr[k];
        float im = s2 * Ci[k];
        const int idxs = kout + l * WID;
        if (EPI == 2) {
            re = aux1[(size_t)img * 2 * HWc + idxs] - re;
            im = aux1[(size_t)img * 2 * HWc + HWc + idxs] - im;
        }
        qre[kout] = re;
        qim[kout] = im;
        if (EPI == 3) {
            out2[(size_t)img * 2 * HWc + idxs]       = re;
            out2[(size_t)img * 2 * HWc + HWc + idxs] = im;
        }
    }
}

// ---------------- fused column FFT kernel (LDS-transposed) ------------------
// Block = 256 threads handles 16 columns of one image (both components).
// Tile [comp][row 320][16+pad 1]: pad 17 -> gcd(17,32)=1 -> 2-way LDS access
// (free on wave64). Cooperative float4 global load/store (64B segments).
// MODE 0: single inverse column FFT (init path).
// MODE 1: forward col FFT + k-space DC (m*(m*K - y)) + inverse col FFT.
template<int SGN>
__device__ __forceinline__ void fft_line_lds(float (*tile)[320][17], int cl, int lane,
                                             const Tw& tw) {
    float vr[5], vi[5];
    const float sgn_in = (lane & 1) ? -1.f : 1.f;
#pragma unroll
    for (int m = 0; m < 5; m++) {
        int n = lane + 64 * m;
        vr[m] = sgn_in * tile[0][n][cl];
        vi[m] = sgn_in * tile[1][n][cl];
    }
    float Cr[5], Ci[5];
    fft320_core<SGN>(vr, vi, Cr, Ci, tw, lane);
    const int k1 = (int)(__brev((unsigned)lane) >> 26);
    const float scale = 0.05590169943749474f;
#pragma unroll
    for (int k = 0; k < 5; k++) {
        int kout = 5 * k1 + k;
        float s2 = (kout & 1) ? -scale : scale;
        tile[0][kout][cl] = s2 * Cr[k];
        tile[1][kout][cl] = s2 * Ci[k];
    }
}

template<int MODE>
__global__ __launch_bounds__(256) void fft_col(const float* __restrict__ in,
                                               float* __restrict__ out,
                                               const float* __restrict__ y,
                                               const float* __restrict__ mask) {
    __shared__ float tile[2][320][17];   // 43.5 KB
    const int tid = threadIdx.x;
    const int img = blockIdx.x / 20;
    const int c0  = (blockIdx.x - img * 20) * 16;
    const size_t ibase = (size_t)img * 2 * HWc;

#pragma unroll
    for (int comp = 0; comp < 2; comp++) {
        const float* p = in + ibase + (size_t)comp * HWc + c0;
        for (int i = tid; i < 1280; i += 256) {
            int row = i >> 2, cg = (i & 3) << 2;
            float4 v = *(const float4*)(p + row * WID + cg);
            float* t = &tile[comp][row][cg];
            t[0] = v.x; t[1] = v.y; t[2] = v.z; t[3] = v.w;
        }
    }
    __syncthreads();

    const int lane = tid & 63;
    const int wv   = tid >> 6;

    if (MODE == 1) {
        Tw twf = make_tw<-1>(lane);
#pragma unroll
        for (int q = 0; q < 4; q++) fft_line_lds<-1>(tile, wv * 4 + q, lane, twf);
        __syncthreads();
        // k-space data consistency, all streams coalesced
        const float* pm  = mask + (size_t)img * HWc + c0;
        const float* pyr = y + ibase + c0;
        const float* pyi = y + ibase + HWc + c0;
        for (int i = tid; i < 1280; i += 256) {
            int row = i >> 2, cg = (i & 3) << 2;
            float4 m4 = *(const float4*)(pm  + row * WID + cg);
            float4 yr = *(const float4*)(pyr + row * WID + cg);
            float4 yi = *(const float4*)(pyi + row * WID + cg);
            float* tr = &tile[0][row][cg];
            float* ti = &tile[1][row][cg];
            tr[0] = m4.x * (m4.x * tr[0] - yr.x);
            tr[1] = m4.y * (m4.y * tr[1] - yr.y);
            tr[2] = m4.z * (m4.z * tr[2] - yr.z);
            tr[3] = m4.w * (m4.w * tr[3] - yr.w);
            ti[0] = m4.x * (m4.x * ti[0] - yi.x);
            ti[1] = m4.y * (m4.y * ti[1] - yi.y);
            ti[2] = m4.z * (m4.z * ti[2] - yi.z);
            ti[3] = m4.w * (m4.w * ti[3] - yi.w);
        }
        __syncthreads();
    }
    {
        Tw twi = make_tw<1>(lane);
#pragma unroll
        for (int q = 0; q < 4; q++) fft_line_lds<1>(tile, wv * 4 + q, lane, twi);
    }
    __syncthreads();
#pragma unroll
    for (int comp = 0; comp < 2; comp++) {
        float* p = out + ibase + (size_t)comp * HWc + c0;
        for (int i = tid; i < 1280; i += 256) {
            int row = i >> 2, cg = (i & 3) << 2;
            const float* t = &tile[comp][row][cg];
            *(float4*)(p + row * WID + cg) = make_float4(t[0], t[1], t[2], t[3]);
        }
    }
}

// ---------------- register+shuffle TV prox ----------------------------------
// One WAVE per 64-col x 42-row tile. Lane = column; each lane holds the whole
// column of {zs,px,py} in registers. Vertical neighbors = adjacent registers;
// horizontal neighbors = shfl. u computed rolling (2 live rows), p updated one
// row behind so py[r] is still OLD when u[r+1] consumes it. Boundary rules
// keyed on GLOBAL coords (identical to reference), so 5-halo shrinkage gives
// exact interior rows [5,37), lanes [5,59). No LDS, no barriers.
constexpr int TVR = 42;   // rows per tile
constexpr int TIR = 32;   // interior rows
constexpr int TIC = 54;   // interior cols

__global__ __launch_bounds__(256) void tv_fused_reg(const float* __restrict__ zs,
                                                    float* __restrict__ out) {
    const int lane = threadIdx.x & 63;
    const int wv   = __builtin_amdgcn_readfirstlane(threadIdx.x >> 6);
    const int w    = blockIdx.x * 4 + wv;           // 32*10*6 = 1920 waves
    const int sl   = w / 60;
    const int rem  = w - sl * 60;
    const int trow = rem / 6;
    const int tcol = rem - trow * 6;
    const int gi0  = trow * TIR - 5;
    const int gj   = tcol * TIC - 5 + lane;
    const bool colin = ((unsigned)gj < (unsigned)WID);
    const float* g = zs + (size_t)sl * HWc;

    float z_[TVR], px_[TVR], py_[TVR];
#pragma unroll
    for (int r = 0; r < TVR; r++) {
        int gi = gi0 + r;
        bool in = colin && ((unsigned)gi < (unsigned)WID);
        float v = 0.f;
        if (in) v = g[gi * WID + gj];
        z_[r] = v; px_[r] = 0.f; py_[r] = 0.f;
    }

    const bool gj_le0 = (gj <= 0);
    const bool gj_hi  = (gj >= WID - 1);
    const bool gx_on  = (gj < WID - 1);

#pragma clang loop unroll(disable)
    for (int it = 0; it < 5; it++) {
        float ucur, unext;
        {   // u[0] (always a halo row; divy value is don't-care for interior gi)
            float pxm = __shfl_up(px_[0], 1);
            float divx = gj_le0 ? px_[0] : (gj_hi ? -pxm : px_[0] - pxm);
            int gi = gi0;
            float divy = (gi <= 0) ? py_[0] : ((gi >= WID - 1) ? -py_[0] : 0.f);
            ucur = z_[0] - LAM_TV * (divx + divy);
        }
#pragma unroll
        for (int r = 0; r < TVR - 1; r++) {
            {   // u[r+1] from OLD p
                int gi1 = gi0 + r + 1;
                float pxm = __shfl_up(px_[r + 1], 1);
                float divx = gj_le0 ? px_[r + 1] : (gj_hi ? -pxm : px_[r + 1] - pxm);
                float divy = (gi1 <= 0) ? py_[r + 1]
                           : ((gi1 >= WID - 1) ? -py_[r] : py_[r + 1] - py_[r]);
                unext = z_[r + 1] - LAM_TV * (divx + divy);
            }
            {   // p[r] update (uses ucur, unext)
                int gi = gi0 + r;
                float un = __shfl_down(ucur, 1);
                float gx = gx_on ? un - ucur : 0.f;
                float gy = (gi < WID - 1) ? unext - ucur : 0.f;
                float px = fmaf(0.25f, gx, px_[r]);
                float py = fmaf(0.25f, gy, py_[r]);
                float n2 = fmaf(px, px, fmaf(py, py, 1e-8f));
                float inv = fminf(rsqrtf(n2), 1.f);
                px_[r] = px * inv;
                py_[r] = py * inv;
            }
            ucur = unext;
        }
        {   // p[TVR-1]: u below unavailable -> gy=0 (halo row, don't-care)
            float un = __shfl_down(ucur, 1);
            float gx = gx_on ? un - ucur : 0.f;
            float px = fmaf(0.25f, gx, px_[TVR - 1]);
            float py = py_[TVR - 1];
            float n2 = fmaf(px, px, fmaf(py, py, 1e-8f));
            float inv = fminf(rsqrtf(n2), 1.f);
            px_[TVR - 1] = px * inv;
            py_[TVR - 1] = py * inv;
        }
    }

    // final u = zs - lam*div(p) on interior; write out
    float* o = out + (size_t)sl * HWc;
    const bool wcol = (lane >= 5) && (lane < 5 + TIC) && colin;
#pragma unroll
    for (int r = 5; r < TVR - 5; r++) {
        int gi = gi0 + r;
        float pxm = __shfl_up(px_[r], 1);
        float divx = gj_le0 ? px_[r] : (gj_hi ? -pxm : px_[r] - pxm);
        float divy = (gi <= 0) ? py_[r]
                   : ((gi >= WID - 1) ? -py_[r - 1] : py_[r] - py_[r - 1]);
        float uf = z_[r] - LAM_TV * (divx + divy);
        if (wcol) o[gi * WID + gj] = uf;
    }
}

// ---------------- fused 3-level Haar + soft-threshold + inverse + FISTA -----
template<int N>
__device__ __forceinline__ void haar_fwd8(const float* in, float* out) {
    const int h = N / 2;
#pragma unroll
    for (int i = 0; i < h; i++)
#pragma unroll
        for (int j = 0; j < h; j++) {
            float a = in[(2 * i) * 8 + 2 * j],     b = in[(2 * i) * 8 + 2 * j + 1];
            float c = in[(2 * i + 1) * 8 + 2 * j], d = in[(2 * i + 1) * 8 + 2 * j + 1];
            out[i * 8 + j]             = (a + b + c + d) * 0.5f;
            out[(i + h) * 8 + j]       = softt((a + b - c - d) * 0.5f);
            out[i * 8 + j + h]         = softt((a - b + c - d) * 0.5f);
            out[(i + h) * 8 + j + h]   = softt((a - b - c + d) * 0.5f);
        }
}

template<int N>
__device__ __forceinline__ void haar_inv8(const float* in, float* out) {
    const int h = N / 2;
#pragma unroll
    for (int i = 0; i < h; i++)
#pragma unroll
        for (int j = 0; j < h; j++) {
            float ll = in[i * 8 + j],       lh = in[(i + h) * 8 + j];
            float hl = in[i * 8 + j + h],   hh = in[(i + h) * 8 + j + h];
            out[(2 * i) * 8 + 2 * j]         = (ll + lh + hl + hh) * 0.5f;
            out[(2 * i) * 8 + 2 * j + 1]     = (ll + lh - hl - hh) * 0.5f;
            out[(2 * i + 1) * 8 + 2 * j]     = (ll - lh + hl - hh) * 0.5f;
            out[(2 * i + 1) * 8 + 2 * j + 1] = (ll - lh - hl + hh) * 0.5f;
        }
}

__global__ __launch_bounds__(256) void wav_fista(const float* __restrict__ u,
                                                 float* __restrict__ x,
                                                 float* __restrict__ z,
                                                 float beta) {
    const int idx = blockIdx.x * 256 + threadIdx.x;   // one per 8x8 block
    const int nb  = WID / 8;       // 40
    const int per = nb * nb;       // 1600
    const int sl  = idx / per;
    const int b   = idx - sl * per;
    const int bi  = (b / nb) * 8, bj = (b % nb) * 8;
    const size_t base = (size_t)sl * HWc + (size_t)bi * WID + bj;

    float v[64], w[64];
    const float* pu = u + base;
#pragma unroll
    for (int r = 0; r < 8; r++) {
        float4 lo = *(const float4*)(pu + r * WID);
        float4 hi = *(const float4*)(pu + r * WID + 4);
        v[r * 8 + 0] = lo.x; v[r * 8 + 1] = lo.y; v[r * 8 + 2] = lo.z; v[r * 8 + 3] = lo.w;
        v[r * 8 + 4] = hi.x; v[r * 8 + 5] = hi.y; v[r * 8 + 6] = hi.z; v[r * 8 + 7] = hi.w;
    }

    haar_fwd8<8>(v, w);
    haar_fwd8<4>(w, v);
    {
        float a = v[0], b2 = v[1], c = v[8], d = v[9];
        v[0] = (a + b2 + c + d) * 0.5f;
        v[8] = softt((a + b2 - c - d) * 0.5f);
        v[1] = softt((a - b2 + c - d) * 0.5f);
        v[9] = softt((a - b2 - c + d) * 0.5f);
    }
    {
        float ll = v[0], lh = v[8], hl = v[1], hh = v[9];
        v[0] = (ll + lh + hl + hh) * 0.5f;
        v[1] = (ll + lh - hl - hh) * 0.5f;
        v[8] = (ll - lh + hl - hh) * 0.5f;
        v[9] = (ll - lh - hl + hh) * 0.5f;
    }
    haar_inv8<4>(v, w);
    haar_inv8<8>(w, v);

    float* px = x + base;
    float* pz = z + base;
#pragma unroll
    for (int r = 0; r < 8; r++) {
        float4 xo_lo = *(const float4*)(px + r * WID);
        float4 xo_hi = *(const float4*)(px + r * WID + 4);
        float4 nlo, nhi, zlo, zhi;
        nlo.x = v[r * 8 + 0]; nlo.y = v[r * 8 + 1]; nlo.z = v[r * 8 + 2]; nlo.w = v[r * 8 + 3];
        nhi.x = v[r * 8 + 4]; nhi.y = v[r * 8 + 5]; nhi.z = v[r * 8 + 6]; nhi.w = v[r * 8 + 7];
        zlo.x = nlo.x + beta * (nlo.x - xo_lo.x);
        zlo.y = nlo.y + beta * (nlo.y - xo_lo.y);
        zlo.z = nlo.z + beta * (nlo.z - xo_lo.z);
        zlo.w = nlo.w + beta * (nlo.w - xo_lo.w);
        zhi.x = nhi.x + beta * (nhi.x - xo_hi.x);
        zhi.y = nhi.y + beta * (nhi.y - xo_hi.y);
        zhi.z = nhi.z + beta * (nhi.z - xo_hi.z);
        zhi.w = nhi.w + beta * (nhi.w - xo_hi.w);
        *(float4*)(px + r * WID)     = nlo;
        *(float4*)(px + r * WID + 4) = nhi;
        *(float4*)(pz + r * WID)     = zlo;
        *(float4*)(pz + r * WID + 4) = zhi;
    }
}

// ---------------- host orchestration ----------------
extern "C" void kernel_launch(void* const* d_in, const int* in_sizes, int n_in,
                              void* d_out, int out_size, void* d_ws, size_t ws_size,
                              hipStream_t stream) {
    const float* y    = (const float*)d_in[0];
    const float* mask = (const float*)d_in[1];
    float* x = (float*)d_out;

    float* ws = (float*)d_ws;
    float* z  = ws;                       // NTOT
    float* t1 = ws + (size_t)NTOT;        // NTOT
    float* t2 = ws + 2 * (size_t)NTOT;    // NTOT

    const int ROW_BLKS = (NIMG * 320) / 4;   // 1280
    const int COL_BLKS = NIMG * 20;          // 320
    const int TV_BLKS  = (NSL * 60) / 4;     // 480
    const int WV_BLKS  = (NSL * 1600) / 256; // 200

    // x0 = ifft2c(y): col-inverse then row-inverse (dual store -> x and z)
    fft_col<0><<<COL_BLKS, 256, 0, stream>>>(y, t1, nullptr, nullptr);
    fft_row<1, 3><<<ROW_BLKS, 256, 0, stream>>>(t1, x, nullptr, z);

    float t = 1.f;
    for (int it = 0; it < 15; it++) {
        // row-forward; then fused (col-forward + DC + col-inverse); then
        // row-inverse with residual epilogue: zs = z - g
        fft_row<-1, 0><<<ROW_BLKS, 256, 0, stream>>>(z, t1, nullptr, nullptr);
        fft_col<1><<<COL_BLKS, 256, 0, stream>>>(t1, t2, y, mask);
        fft_row<1, 2><<<ROW_BLKS, 256, 0, stream>>>(t2, t1, z, nullptr);

        // TV prox: 5 dual iterations, register+shuffle, one wave per tile
        tv_fused_reg<<<TV_BLKS, 256, 0, stream>>>(t1, t2);

        // 3-level wavelet shrinkage + FISTA momentum
        float tn   = (1.f + sqrtf(1.f + 4.f * t * t)) * 0.5f;
        float beta = (t - 1.f) / tn;
        t = tn;
        wav_fista<<<WV_BLKS, 256, 0, stream>>>(t2, x, z, beta);
    }
    (void)in_sizes; (void)n_in; (void)out_size; (void)ws_size;
}

// Round 4
// 1601.443 us; speedup vs baseline: 2.7131x; 1.2284x over previous
//
#include <hip/hip_runtime.h>
#include <math.h>

constexpr int WID  = 320;
constexpr int HWc  = 320 * 320;        // 102400
constexpr int NIMG = 16;
constexpr int NSL  = 32;               // B*C slices for TV/DWT
constexpr int NTOT = NIMG * 2 * HWc;   // 3276800 floats per full array
constexpr float LAM_TV  = 0.005f;
constexpr float LAM_WAV = 0.005f;

__device__ __forceinline__ float softt(float v) {
    float a = fmaxf(fabsf(v) - LAM_WAV, 0.f);
    return copysignf(a, v);
}

// ================= 320-point FFT core (shared by row & col kernels) =========
// 320 = 5 (register DFT) x 64 (lane FFT via shfl_xor). Centered transform via
// (-1)^n modulation at load and (-1)^k at store (N even; handled by callers).
struct Tw { float tc, ts; float stc[6], sts[6]; };

template<int SGN>
__device__ __forceinline__ Tw make_tw(int lane) {
    Tw tw;
    __sincosf((float)SGN * 6.283185307179586f * (float)lane / 320.f, &tw.ts, &tw.tc);
#pragma unroll
    for (int s = 0; s < 6; s++) {
        int h = 32 >> s;
        int j = lane & (h - 1);
        float ang = (float)SGN * 3.14159265358979323f * (float)j / (float)h;
        __sincosf(ang, &tw.sts[s], &tw.stc[s]);
    }
    return tw;
}

// in: vr/vi hold elements n = lane + 64m in slot m (already sign-modulated).
// out: Cr/Ci hold X[5*bitrev6(lane) + k] in slot k (unscaled).
template<int SGN>
__device__ __forceinline__ void fft320_core(const float (&vr)[5], const float (&vi)[5],
                                            float (&Cr)[5], float (&Ci)[5],
                                            const Tw& tw, int lane) {
    const float cw1 = 0.30901699437494745f, sw1 = 0.9510565162951535f;
    const float cw2 = -0.8090169943749475f, sw2 = 0.5877852522924731f;
    const float cwt[5] = {1.f, cw1, cw2, cw2, cw1};
    const float swt[5] = {0.f, sw1, sw2, -sw2, -sw1};
    Cr[0] = vr[0] + vr[1] + vr[2] + vr[3] + vr[4];
    Ci[0] = vi[0] + vi[1] + vi[2] + vi[3] + vi[4];
#pragma unroll
    for (int k = 1; k < 5; k++) {
        float ar = vr[0], ai = vi[0];
#pragma unroll
        for (int m = 1; m < 5; m++) {
            int j = (m * k) % 5;
            float wr_ = cwt[j], wi_ = (float)SGN * swt[j];
            ar += vr[m] * wr_ - vi[m] * wi_;
            ai += vr[m] * wi_ + vi[m] * wr_;
        }
        Cr[k] = ar; Ci[k] = ai;
    }
    // twiddle W_320^{lane*k}
    float twr = 1.f, twi = 0.f;
#pragma unroll
    for (int k = 1; k < 5; k++) {
        float nr = twr * tw.tc - twi * tw.ts;
        twi = twr * tw.ts + twi * tw.tc;
        twr = nr;
        float r = Cr[k] * twr - Ci[k] * twi;
        Ci[k]   = Cr[k] * twi + Ci[k] * twr;
        Cr[k]   = r;
    }
    // 6-stage radix-2 DIF across 64 lanes
#pragma unroll
    for (int s = 0; s < 6; s++) {
        int h = 32 >> s;
        bool up = (lane & h) != 0;
#pragma unroll
        for (int k = 0; k < 5; k++) {
            float orr = __shfl_xor(Cr[k], h);
            float oii = __shfl_xor(Ci[k], h);
            if (up) {
                float dr = orr - Cr[k], di = oii - Ci[k];
                Cr[k] = dr * tw.stc[s] - di * tw.sts[s];
                Ci[k] = dr * tw.sts[s] + di * tw.stc[s];
            } else {
                Cr[k] += orr;
                Ci[k] += oii;
            }
        }
    }
}

// ---------------- row FFT pass (coalesced; lines are contiguous rows) -------
// EPI: 0 = plain store
//      2 = residual store: out = aux1 - val   (aux1 = z)
//      3 = dual store:     out and out2 both get val
template<int SGN, int EPI>
__global__ __launch_bounds__(256) void fft_row(const float* __restrict__ in,
                                               float* __restrict__ out,
                                               const float* __restrict__ aux1,
                                               float* __restrict__ out2) {
    const int lane = threadIdx.x & 63;
    const int wv   = threadIdx.x >> 6;
    const int L    = blockIdx.x * 4 + wv;
    const int img  = L / 320;
    const int l    = L - img * 320;
    const float* pre = in + (size_t)img * 2 * HWc + (size_t)l * WID;
    const float* pim = pre + HWc;

    float vr[5], vi[5];
    const float sgn_in = (lane & 1) ? -1.f : 1.f;
#pragma unroll
    for (int m = 0; m < 5; m++) {
        int n = lane + 64 * m;
        vr[m] = sgn_in * pre[n];
        vi[m] = sgn_in * pim[n];
    }
    Tw tw = make_tw<SGN>(lane);
    float Cr[5], Ci[5];
    fft320_core<SGN>(vr, vi, Cr, Ci, tw, lane);

    const int k1 = (int)(__brev((unsigned)lane) >> 26);
    float* qre = out + (size_t)img * 2 * HWc + (size_t)l * WID;
    float* qim = qre + HWc;
    const float scale = 0.05590169943749474f;  // 1/sqrt(320)
#pragma unroll
    for (int k = 0; k < 5; k++) {
        int kout = 5 * k1 + k;
        float s2 = (kout & 1) ? -scale : scale;
        float re = s2 * Cr[k];
        float im = s2 * Ci[k];
        const int idxs = kout + l * WID;
        if (EPI == 2) {
            re = aux1[(size_t)img * 2 * HWc + idxs] - re;
            im = aux1[(size_t)img * 2 * HWc + HWc + idxs] - im;
        }
        qre[kout] = re;
        qim[kout] = im;
        if (EPI == 3) {
            out2[(size_t)img * 2 * HWc + idxs]       = re;
            out2[(size_t)img * 2 * HWc + HWc + idxs] = im;
        }
    }
}

// ---------------- fused column FFT kernel (LDS-transposed) ------------------
// Block = 256 threads handles 16 columns of one image (both components).
// Tile [comp][row 320][16+pad 1]: pad 17 -> gcd(17,32)=1 -> 2-way LDS access
// (free on wave64). Cooperative float4 global load/store (64B segments).
// MODE 0: single inverse column FFT (init path).
// MODE 1: forward col FFT + k-space DC (m*(m*K - y)) + inverse col FFT.
template<int SGN>
__device__ __forceinline__ void fft_line_lds(float (*tile)[320][17], int cl, int lane,
                                             const Tw& tw) {
    float vr[5], vi[5];
    const float sgn_in = (lane & 1) ? -1.f : 1.f;
#pragma unroll
    for (int m = 0; m < 5; m++) {
        int n = lane + 64 * m;
        vr[m] = sgn_in * tile[0][n][cl];
        vi[m] = sgn_in * tile[1][n][cl];
    }
    float Cr[5], Ci[5];
    fft320_core<SGN>(vr, vi, Cr, Ci, tw, lane);
    const int k1 = (int)(__brev((unsigned)lane) >> 26);
    const float scale = 0.05590169943749474f;
#pragma unroll
    for (int k = 0; k < 5; k++) {
        int kout = 5 * k1 + k;
        float s2 = (kout & 1) ? -scale : scale;
        tile[0][kout][cl] = s2 * Cr[k];
        tile[1][kout][cl] = s2 * Ci[k];
    }
}

template<int MODE>
__global__ __launch_bounds__(256) void fft_col(const float* __restrict__ in,
                                               float* __restrict__ out,
                                               const float* __restrict__ y,
                                               const float* __restrict__ mask) {
    __shared__ float tile[2][320][17];   // 43.5 KB
    const int tid = threadIdx.x;
    const int img = blockIdx.x / 20;
    const int c0  = (blockIdx.x - img * 20) * 16;
    const size_t ibase = (size_t)img * 2 * HWc;

#pragma unroll
    for (int comp = 0; comp < 2; comp++) {
        const float* p = in + ibase + (size_t)comp * HWc + c0;
        for (int i = tid; i < 1280; i += 256) {
            int row = i >> 2, cg = (i & 3) << 2;
            float4 v = *(const float4*)(p + row * WID + cg);
            float* t = &tile[comp][row][cg];
            t[0] = v.x; t[1] = v.y; t[2] = v.z; t[3] = v.w;
        }
    }
    __syncthreads();

    const int lane = tid & 63;
    const int wv   = tid >> 6;

    if (MODE == 1) {
        Tw twf = make_tw<-1>(lane);
#pragma unroll
        for (int q = 0; q < 4; q++) fft_line_lds<-1>(tile, wv * 4 + q, lane, twf);
        __syncthreads();
        // k-space data consistency, all streams coalesced
        const float* pm  = mask + (size_t)img * HWc + c0;
        const float* pyr = y + ibase + c0;
        const float* pyi = y + ibase + HWc + c0;
        for (int i = tid; i < 1280; i += 256) {
            int row = i >> 2, cg = (i & 3) << 2;
            float4 m4 = *(const float4*)(pm  + row * WID + cg);
            float4 yr = *(const float4*)(pyr + row * WID + cg);
            float4 yi = *(const float4*)(pyi + row * WID + cg);
            float* tr = &tile[0][row][cg];
            float* ti = &tile[1][row][cg];
            tr[0] = m4.x * (m4.x * tr[0] - yr.x);
            tr[1] = m4.y * (m4.y * tr[1] - yr.y);
            tr[2] = m4.z * (m4.z * tr[2] - yr.z);
            tr[3] = m4.w * (m4.w * tr[3] - yr.w);
            ti[0] = m4.x * (m4.x * ti[0] - yi.x);
            ti[1] = m4.y * (m4.y * ti[1] - yi.y);
            ti[2] = m4.z * (m4.z * ti[2] - yi.z);
            ti[3] = m4.w * (m4.w * ti[3] - yi.w);
        }
        __syncthreads();
    }
    {
        Tw twi = make_tw<1>(lane);
#pragma unroll
        for (int q = 0; q < 4; q++) fft_line_lds<1>(tile, wv * 4 + q, lane, twi);
    }
    __syncthreads();
#pragma unroll
    for (int comp = 0; comp < 2; comp++) {
        float* p = out + ibase + (size_t)comp * HWc + c0;
        for (int i = tid; i < 1280; i += 256) {
            int row = i >> 2, cg = (i & 3) << 2;
            const float* t = &tile[comp][row][cg];
            *(float4*)(p + row * WID + cg) = make_float4(t[0], t[1], t[2], t[3]);
        }
    }
}

// ---------------- register+shuffle TV prox ----------------------------------
// One WAVE per 64-col x 26-row tile. Lane = column; each lane holds its
// column of {zs,px,py,u} in registers. Vertical neighbors = adjacent
// registers; horizontal = shfl. Per dual iteration: (1) ALL u rows computed
// first (only depend on old p -> fully independent -> max ILP), then (2) ALL
// p rows updated (independent given u). Boundary rules keyed on GLOBAL
// coords (identical to reference); 5-halo shrinkage gives exact interior
// rows [5,21), lanes [5,59). No LDS, no barriers.
constexpr int TIR = 16;   // interior rows
constexpr int TVR = TIR + 10;   // 26 rows per tile
constexpr int TIC = 54;   // interior cols
constexpr int TPS = (WID / TIR) * 6;   // 120 tiles per slice

__global__ __launch_bounds__(256) void tv_fused_reg(const float* __restrict__ zs,
                                                    float* __restrict__ out) {
    const int lane = threadIdx.x & 63;
    const int wv   = __builtin_amdgcn_readfirstlane(threadIdx.x >> 6);
    const int w    = blockIdx.x * 4 + wv;           // 32*120 = 3840 waves
    const int sl   = w / TPS;
    const int rem  = w - sl * TPS;
    const int trow = rem / 6;
    const int tcol = rem - trow * 6;
    const int gi0  = trow * TIR - 5;
    const int gj   = tcol * TIC - 5 + lane;
    const bool colin = ((unsigned)gj < (unsigned)WID);
    const float* g = zs + (size_t)sl * HWc;

    float z_[TVR], px_[TVR], py_[TVR], u_[TVR];
#pragma unroll
    for (int r = 0; r < TVR; r++) {
        int gi = gi0 + r;
        bool in = colin && ((unsigned)gi < (unsigned)WID);
        float v = 0.f;
        if (in) v = g[gi * WID + gj];
        z_[r] = v; px_[r] = 0.f; py_[r] = 0.f;
    }

    const bool gj_le0 = (gj <= 0);
    const bool gj_hi  = (gj >= WID - 1);
    const bool gx_on  = (gj < WID - 1);

#pragma clang loop unroll(disable)
    for (int it = 0; it < 5; it++) {
        // pass 1: u[r] = z[r] - lam*div(p)[r]  -- all rows independent
#pragma unroll
        for (int r = 0; r < TVR; r++) {
            int gi = gi0 + r;
            float pxm = __shfl_up(px_[r], 1);
            float divx = gj_le0 ? px_[r] : (gj_hi ? -pxm : px_[r] - pxm);
            float pym = (r > 0) ? py_[r - 1] : py_[0];   // r=0 is halo: don't-care
            float divy = (gi <= 0) ? py_[r]
                       : ((gi >= WID - 1) ? -pym : py_[r] - pym);
            u_[r] = z_[r] - LAM_TV * (divx + divy);
        }
        // pass 2: p[r] = proj(p[r] + tau*grad(u)[r]) -- all rows independent
#pragma unroll
        for (int r = 0; r < TVR; r++) {
            int gi = gi0 + r;
            float un = __shfl_down(u_[r], 1);
            float ub = (r < TVR - 1) ? u_[r + 1] : u_[r];  // last row halo: don't-care
            float gx = gx_on ? un - u_[r] : 0.f;
            float gy = (gi < WID - 1 && r < TVR - 1) ? ub - u_[r] : 0.f;
            float px = fmaf(0.25f, gx, px_[r]);
            float py = fmaf(0.25f, gy, py_[r]);
            float n2 = fmaf(px, px, fmaf(py, py, 1e-8f));
            float inv = fminf(rsqrtf(n2), 1.f);
            px_[r] = px * inv;
            py_[r] = py * inv;
        }
    }

    // final u = zs - lam*div(p) on interior; write out
    float* o = out + (size_t)sl * HWc;
    const bool wcol = (lane >= 5) && (lane < 5 + TIC) && colin;
#pragma unroll
    for (int r = 5; r < TVR - 5; r++) {
        int gi = gi0 + r;
        float pxm = __shfl_up(px_[r], 1);
        float divx = gj_le0 ? px_[r] : (gj_hi ? -pxm : px_[r] - pxm);
        float divy = (gi <= 0) ? py_[r]
                   : ((gi >= WID - 1) ? -py_[r - 1] : py_[r] - py_[r - 1]);
        float uf = z_[r] - LAM_TV * (divx + divy);
        if (wcol) o[gi * WID + gj] = uf;
    }
}

// ---------------- fused 3-level Haar + soft-threshold + inverse + FISTA -----
template<int N>
__device__ __forceinline__ void haar_fwd8(const float* in, float* out) {
    const int h = N / 2;
#pragma unroll
    for (int i = 0; i < h; i++)
#pragma unroll
        for (int j = 0; j < h; j++) {
            float a = in[(2 * i) * 8 + 2 * j],     b = in[(2 * i) * 8 + 2 * j + 1];
            float c = in[(2 * i + 1) * 8 + 2 * j], d = in[(2 * i + 1) * 8 + 2 * j + 1];
            out[i * 8 + j]             = (a + b + c + d) * 0.5f;
            out[(i + h) * 8 + j]       = softt((a + b - c - d) * 0.5f);
            out[i * 8 + j + h]         = softt((a - b + c - d) * 0.5f);
            out[(i + h) * 8 + j + h]   = softt((a - b - c + d) * 0.5f);
        }
}

template<int N>
__device__ __forceinline__ void haar_inv8(const float* in, float* out) {
    const int h = N / 2;
#pragma unroll
    for (int i = 0; i < h; i++)
#pragma unroll
        for (int j = 0; j < h; j++) {
            float ll = in[i * 8 + j],       lh = in[(i + h) * 8 + j];
            float hl = in[i * 8 + j + h],   hh = in[(i + h) * 8 + j + h];
            out[(2 * i) * 8 + 2 * j]         = (ll + lh + hl + hh) * 0.5f;
            out[(2 * i) * 8 + 2 * j + 1]     = (ll + lh - hl - hh) * 0.5f;
            out[(2 * i + 1) * 8 + 2 * j]     = (ll - lh + hl - hh) * 0.5f;
            out[(2 * i + 1) * 8 + 2 * j + 1] = (ll - lh - hl + hh) * 0.5f;
        }
}

__global__ __launch_bounds__(256) void wav_fista(const float* __restrict__ u,
                                                 float* __restrict__ x,
                                                 float* __restrict__ z,
                                                 float beta) {
    const int idx = blockIdx.x * 256 + threadIdx.x;   // one per 8x8 block
    const int nb  = WID / 8;       // 40
    const int per = nb * nb;       // 1600
    const int sl  = idx / per;
    const int b   = idx - sl * per;
    const int bi  = (b / nb) * 8, bj = (b % nb) * 8;
    const size_t base = (size_t)sl * HWc + (size_t)bi * WID + bj;

    float v[64], w[64];
    const float* pu = u + base;
#pragma unroll
    for (int r = 0; r < 8; r++) {
        float4 lo = *(const float4*)(pu + r * WID);
        float4 hi = *(const float4*)(pu + r * WID + 4);
        v[r * 8 + 0] = lo.x; v[r * 8 + 1] = lo.y; v[r * 8 + 2] = lo.z; v[r * 8 + 3] = lo.w;
        v[r * 8 + 4] = hi.x; v[r * 8 + 5] = hi.y; v[r * 8 + 6] = hi.z; v[r * 8 + 7] = hi.w;
    }

    haar_fwd8<8>(v, w);
    haar_fwd8<4>(w, v);
    {
        float a = v[0], b2 = v[1], c = v[8], d = v[9];
        v[0] = (a + b2 + c + d) * 0.5f;
        v[8] = softt((a + b2 - c - d) * 0.5f);
        v[1] = softt((a - b2 + c - d) * 0.5f);
        v[9] = softt((a - b2 - c + d) * 0.5f);
    }
    {
        float ll = v[0], lh = v[8], hl = v[1], hh = v[9];
        v[0] = (ll + lh + hl + hh) * 0.5f;
        v[1] = (ll + lh - hl - hh) * 0.5f;
        v[8] = (ll - lh + hl - hh) * 0.5f;
        v[9] = (ll - lh - hl + hh) * 0.5f;
    }
    haar_inv8<4>(v, w);
    haar_inv8<8>(w, v);

    float* px = x + base;
    float* pz = z + base;
#pragma unroll
    for (int r = 0; r < 8; r++) {
        float4 xo_lo = *(const float4*)(px + r * WID);
        float4 xo_hi = *(const float4*)(px + r * WID + 4);
        float4 nlo, nhi, zlo, zhi;
        nlo.x = v[r * 8 + 0]; nlo.y = v[r * 8 + 1]; nlo.z = v[r * 8 + 2]; nlo.w = v[r * 8 + 3];
        nhi.x = v[r * 8 + 4]; nhi.y = v[r * 8 + 5]; nhi.z = v[r * 8 + 6]; nhi.w = v[r * 8 + 7];
        zlo.x = nlo.x + beta * (nlo.x - xo_lo.x);
        zlo.y = nlo.y + beta * (nlo.y - xo_lo.y);
        zlo.z = nlo.z + beta * (nlo.z - xo_lo.z);
        zlo.w = nlo.w + beta * (nlo.w - xo_lo.w);
        zhi.x = nhi.x + beta * (nhi.x - xo_hi.x);
        zhi.y = nhi.y + beta * (nhi.y - xo_hi.y);
        zhi.z = nhi.z + beta * (nhi.z - xo_hi.z);
        zhi.w = nhi.w + beta * (nhi.w - xo_hi.w);
        *(float4*)(px + r * WID)     = nlo;
        *(float4*)(px + r * WID + 4) = nhi;
        *(float4*)(pz + r * WID)     = zlo;
        *(float4*)(pz + r * WID + 4) = zhi;
    }
}

// ---------------- host orchestration ----------------
extern "C" void kernel_launch(void* const* d_in, const int* in_sizes, int n_in,
                              void* d_out, int out_size, void* d_ws, size_t ws_size,
                              hipStream_t stream) {
    const float* y    = (const float*)d_in[0];
    const float* mask = (const float*)d_in[1];
    float* x = (float*)d_out;

    float* ws = (float*)d_ws;
    float* z  = ws;                       // NTOT
    float* t1 = ws + (size_t)NTOT;        // NTOT
    float* t2 = ws + 2 * (size_t)NTOT;    // NTOT

    const int ROW_BLKS = (NIMG * 320) / 4;   // 1280
    const int COL_BLKS = NIMG * 20;          // 320
    const int TV_BLKS  = (NSL * TPS) / 4;    // 960
    const int WV_BLKS  = (NSL * 1600) / 256; // 200

    // x0 = ifft2c(y): col-inverse then row-inverse (dual store -> x and z)
    fft_col<0><<<COL_BLKS, 256, 0, stream>>>(y, t1, nullptr, nullptr);
    fft_row<1, 3><<<ROW_BLKS, 256, 0, stream>>>(t1, x, nullptr, z);

    float t = 1.f;
    for (int it = 0; it < 15; it++) {
        // row-forward; then fused (col-forward + DC + col-inverse); then
        // row-inverse with residual epilogue: zs = z - g
        fft_row<-1, 0><<<ROW_BLKS, 256, 0, stream>>>(z, t1, nullptr, nullptr);
        fft_col<1><<<COL_BLKS, 256, 0, stream>>>(t1, t2, y, mask);
        fft_row<1, 2><<<ROW_BLKS, 256, 0, stream>>>(t2, t1, z, nullptr);

        // TV prox: 5 dual iterations, register+shuffle, one wave per tile
        tv_fused_reg<<<TV_BLKS, 256, 0, stream>>>(t1, t2);

        // 3-level wavelet shrinkage + FISTA momentum
        float tn   = (1.f + sqrtf(1.f + 4.f * t * t)) * 0.5f;
        float beta = (t - 1.f) / tn;
        t = tn;
        wav_fista<<<WV_BLKS, 256, 0, stream>>>(t2, x, z, beta);
    }
    (void)in_sizes; (void)n_in; (void)out_size; (void)ws_size;
}

// Round 5
// 1576.432 us; speedup vs baseline: 2.7561x; 1.0159x over previous
//
#include <hip/hip_runtime.h>
#include <math.h>

constexpr int WID  = 320;
constexpr int HWc  = 320 * 320;        // 102400
constexpr int NIMG = 16;
constexpr int NSL  = 32;               // B*C slices for TV/DWT
constexpr int NTOT = NIMG * 2 * HWc;   // 3276800 floats per full array
constexpr float LAM_TV  = 0.005f;
constexpr float LAM_WAV = 0.005f;

__device__ __forceinline__ float softt(float v) {
    float a = fmaxf(fabsf(v) - LAM_WAV, 0.f);
    return copysignf(a, v);
}

// ================= 320-point FFT core (shared by row & col kernels) =========
// 320 = 5 (register DFT) x 64 (lane FFT via shfl_xor). Centered transform via
// (-1)^n modulation at load and (-1)^k at store (N even; handled by callers).
struct Tw { float tc, ts; float stc[6], sts[6]; };

template<int SGN>
__device__ __forceinline__ Tw make_tw(int lane) {
    Tw tw;
    __sincosf((float)SGN * 6.283185307179586f * (float)lane / 320.f, &tw.ts, &tw.tc);
#pragma unroll
    for (int s = 0; s < 6; s++) {
        int h = 32 >> s;
        int j = lane & (h - 1);
        float ang = (float)SGN * 3.14159265358979323f * (float)j / (float)h;
        __sincosf(ang, &tw.sts[s], &tw.stc[s]);
    }
    return tw;
}

// in: vr/vi hold elements n = lane + 64m in slot m (already sign-modulated).
// out: Cr/Ci hold X[5*bitrev6(lane) + k] in slot k (unscaled).
template<int SGN>
__device__ __forceinline__ void fft320_core(const float (&vr)[5], const float (&vi)[5],
                                            float (&Cr)[5], float (&Ci)[5],
                                            const Tw& tw, int lane) {
    const float cw1 = 0.30901699437494745f, sw1 = 0.9510565162951535f;
    const float cw2 = -0.8090169943749475f, sw2 = 0.5877852522924731f;
    const float cwt[5] = {1.f, cw1, cw2, cw2, cw1};
    const float swt[5] = {0.f, sw1, sw2, -sw2, -sw1};
    Cr[0] = vr[0] + vr[1] + vr[2] + vr[3] + vr[4];
    Ci[0] = vi[0] + vi[1] + vi[2] + vi[3] + vi[4];
#pragma unroll
    for (int k = 1; k < 5; k++) {
        float ar = vr[0], ai = vi[0];
#pragma unroll
        for (int m = 1; m < 5; m++) {
            int j = (m * k) % 5;
            float wr_ = cwt[j], wi_ = (float)SGN * swt[j];
            ar += vr[m] * wr_ - vi[m] * wi_;
            ai += vr[m] * wi_ + vi[m] * wr_;
        }
        Cr[k] = ar; Ci[k] = ai;
    }
    // twiddle W_320^{lane*k}
    float twr = 1.f, twi = 0.f;
#pragma unroll
    for (int k = 1; k < 5; k++) {
        float nr = twr * tw.tc - twi * tw.ts;
        twi = twr * tw.ts + twi * tw.tc;
        twr = nr;
        float r = Cr[k] * twr - Ci[k] * twi;
        Ci[k]   = Cr[k] * twi + Ci[k] * twr;
        Cr[k]   = r;
    }
    // 6-stage radix-2 DIF across 64 lanes
#pragma unroll
    for (int s = 0; s < 6; s++) {
        int h = 32 >> s;
        bool up = (lane & h) != 0;
#pragma unroll
        for (int k = 0; k < 5; k++) {
            float orr = __shfl_xor(Cr[k], h);
            float oii = __shfl_xor(Ci[k], h);
            if (up) {
                float dr = orr - Cr[k], di = oii - Ci[k];
                Cr[k] = dr * tw.stc[s] - di * tw.sts[s];
                Ci[k] = dr * tw.sts[s] + di * tw.stc[s];
            } else {
                Cr[k] += orr;
                Ci[k] += oii;
            }
        }
    }
}

// ---------------- row FFT pass (coalesced; lines are contiguous rows) -------
// EPI: 0 = plain store
//      2 = residual store: out = aux1 - val   (aux1 = z)
//      3 = dual store:     out and out2 both get val
template<int SGN, int EPI>
__global__ __launch_bounds__(256) void fft_row(const float* __restrict__ in,
                                               float* __restrict__ out,
                                               const float* __restrict__ aux1,
                                               float* __restrict__ out2) {
    const int lane = threadIdx.x & 63;
    const int wv   = threadIdx.x >> 6;
    const int L    = blockIdx.x * 4 + wv;
    const int img  = L / 320;
    const int l    = L - img * 320;
    const float* pre = in + (size_t)img * 2 * HWc + (size_t)l * WID;
    const float* pim = pre + HWc;

    float vr[5], vi[5];
    const float sgn_in = (lane & 1) ? -1.f : 1.f;
#pragma unroll
    for (int m = 0; m < 5; m++) {
        int n = lane + 64 * m;
        vr[m] = sgn_in * pre[n];
        vi[m] = sgn_in * pim[n];
    }
    Tw tw = make_tw<SGN>(lane);
    float Cr[5], Ci[5];
    fft320_core<SGN>(vr, vi, Cr, Ci, tw, lane);

    const int k1 = (int)(__brev((unsigned)lane) >> 26);
    float* qre = out + (size_t)img * 2 * HWc + (size_t)l * WID;
    float* qim = qre + HWc;
    const float scale = 0.05590169943749474f;  // 1/sqrt(320)
#pragma unroll
    for (int k = 0; k < 5; k++) {
        int kout = 5 * k1 + k;
        float s2 = (kout & 1) ? -scale : scale;
        float re = s2 * Cr[k];
        float im = s2 * Ci[k];
        const int idxs = kout + l * WID;
        if (EPI == 2) {
            re = aux1[(size_t)img * 2 * HWc + idxs] - re;
            im = aux1[(size_t)img * 2 * HWc + HWc + idxs] - im;
        }
        qre[kout] = re;
        qim[kout] = im;
        if (EPI == 3) {
            out2[(size_t)img * 2 * HWc + idxs]       = re;
            out2[(size_t)img * 2 * HWc + HWc + idxs] = im;
        }
    }
}

// ---------------- fused column FFT kernel (LDS-transposed) ------------------
// Block = 256 threads handles 16 columns of one image (both components).
// Tile [comp][row 320][16+pad 1]: pad 17 -> gcd(17,32)=1 -> 2-way LDS access
// (free on wave64). Cooperative float4 global load/store (64B segments).
// MODE 0: single inverse column FFT (init path).
// MODE 1: forward col FFT + k-space DC (m*(m*K - y)) + inverse col FFT.
template<int SGN>
__device__ __forceinline__ void fft_line_lds(float (*tile)[320][17], int cl, int lane,
                                             const Tw& tw) {
    float vr[5], vi[5];
    const float sgn_in = (lane & 1) ? -1.f : 1.f;
#pragma unroll
    for (int m = 0; m < 5; m++) {
        int n = lane + 64 * m;
        vr[m] = sgn_in * tile[0][n][cl];
        vi[m] = sgn_in * tile[1][n][cl];
    }
    float Cr[5], Ci[5];
    fft320_core<SGN>(vr, vi, Cr, Ci, tw, lane);
    const int k1 = (int)(__brev((unsigned)lane) >> 26);
    const float scale = 0.05590169943749474f;
#pragma unroll
    for (int k = 0; k < 5; k++) {
        int kout = 5 * k1 + k;
        float s2 = (kout & 1) ? -scale : scale;
        tile[0][kout][cl] = s2 * Cr[k];
        tile[1][kout][cl] = s2 * Ci[k];
    }
}

template<int MODE>
__global__ __launch_bounds__(256) void fft_col(const float* __restrict__ in,
                                               float* __restrict__ out,
                                               const float* __restrict__ y,
                                               const float* __restrict__ mask) {
    __shared__ float tile[2][320][17];   // 43.5 KB
    const int tid = threadIdx.x;
    const int img = blockIdx.x / 20;
    const int c0  = (blockIdx.x - img * 20) * 16;
    const size_t ibase = (size_t)img * 2 * HWc;

#pragma unroll
    for (int comp = 0; comp < 2; comp++) {
        const float* p = in + ibase + (size_t)comp * HWc + c0;
        for (int i = tid; i < 1280; i += 256) {
            int row = i >> 2, cg = (i & 3) << 2;
            float4 v = *(const float4*)(p + row * WID + cg);
            float* t = &tile[comp][row][cg];
            t[0] = v.x; t[1] = v.y; t[2] = v.z; t[3] = v.w;
        }
    }
    __syncthreads();

    const int lane = tid & 63;
    const int wv   = tid >> 6;

    if (MODE == 1) {
        Tw twf = make_tw<-1>(lane);
#pragma unroll
        for (int q = 0; q < 4; q++) fft_line_lds<-1>(tile, wv * 4 + q, lane, twf);
        __syncthreads();
        // k-space data consistency, all streams coalesced
        const float* pm  = mask + (size_t)img * HWc + c0;
        const float* pyr = y + ibase + c0;
        const float* pyi = y + ibase + HWc + c0;
        for (int i = tid; i < 1280; i += 256) {
            int row = i >> 2, cg = (i & 3) << 2;
            float4 m4 = *(const float4*)(pm  + row * WID + cg);
            float4 yr = *(const float4*)(pyr + row * WID + cg);
            float4 yi = *(const float4*)(pyi + row * WID + cg);
            float* tr = &tile[0][row][cg];
            float* ti = &tile[1][row][cg];
            tr[0] = m4.x * (m4.x * tr[0] - yr.x);
            tr[1] = m4.y * (m4.y * tr[1] - yr.y);
            tr[2] = m4.z * (m4.z * tr[2] - yr.z);
            tr[3] = m4.w * (m4.w * tr[3] - yr.w);
            ti[0] = m4.x * (m4.x * ti[0] - yi.x);
            ti[1] = m4.y * (m4.y * ti[1] - yi.y);
            ti[2] = m4.z * (m4.z * ti[2] - yi.z);
            ti[3] = m4.w * (m4.w * ti[3] - yi.w);
        }
        __syncthreads();
    }
    {
        Tw twi = make_tw<1>(lane);
#pragma unroll
        for (int q = 0; q < 4; q++) fft_line_lds<1>(tile, wv * 4 + q, lane, twi);
    }
    __syncthreads();
#pragma unroll
    for (int comp = 0; comp < 2; comp++) {
        float* p = out + ibase + (size_t)comp * HWc + c0;
        for (int i = tid; i < 1280; i += 256) {
            int row = i >> 2, cg = (i & 3) << 2;
            const float* t = &tile[comp][row][cg];
            *(float4*)(p + row * WID + cg) = make_float4(t[0], t[1], t[2], t[3]);
        }
    }
}

// ============ fused TV prox + 3-level Haar shrinkage + FISTA ================
// One WAVE per tile: interior 16 rows x 48 cols (8x8-block aligned), halo 8
// cols each side (lane = col, interior lanes [8,56)), vertical halo 5 rows.
// TV: 5 dual iterations in registers (shfl for horizontal neighbors).
// Wavelet: interior is whole 8x8 blocks; 3 forward Haar levels via
// shfl_xor(1/2/4) with REPLICATED sum/diff in both partner lanes -> the
// inverse transform is shuffle-free (each lane reconstructs its own column).
// Lane groups [8,56) are closed under xor(1,2,4) so halo lanes never
// contaminate valid ones. FISTA epilogue fused (read x_old, write x, z).
constexpr int TIR = 16;                 // interior rows
constexpr int TVR = TIR + 10;           // 26 rows per tile
constexpr int TIC = 48;                 // interior cols
constexpr int TCOLS = 7;                // ceil(320/48), last tile interior 32
constexpr int TROWS = WID / TIR;        // 20
constexpr int TPS = TROWS * TCOLS;      // 140 tiles per slice

__global__ __launch_bounds__(256) void tv_wav_fista(const float* __restrict__ zs,
                                                    float* __restrict__ x,
                                                    float* __restrict__ z,
                                                    float beta) {
    const int lane = threadIdx.x & 63;
    const int wv   = __builtin_amdgcn_readfirstlane(threadIdx.x >> 6);
    const int w    = blockIdx.x * 4 + wv;           // 32*140 = 4480 waves
    const int sl   = w / TPS;
    const int rem  = w - sl * TPS;
    const int trow = rem / TCOLS;
    const int tcol = rem - trow * TCOLS;
    const int gi0  = trow * TIR - 5;
    const int gj   = tcol * TIC - 8 + lane;         // interior at lanes [8,56)
    const bool colin = ((unsigned)gj < (unsigned)WID);
    const float* g = zs + (size_t)sl * HWc;

    float z_[TVR], px_[TVR], py_[TVR], u_[TVR];
#pragma unroll
    for (int r = 0; r < TVR; r++) {
        int gi = gi0 + r;
        bool in = colin && ((unsigned)gi < (unsigned)WID);
        float v = 0.f;
        if (in) v = g[gi * WID + gj];
        z_[r] = v; px_[r] = 0.f; py_[r] = 0.f;
    }

    const bool gj_le0 = (gj <= 0);
    const bool gj_hi  = (gj >= WID - 1);
    const bool gx_on  = (gj < WID - 1);

#pragma clang loop unroll(disable)
    for (int it = 0; it < 5; it++) {
        // pass 1: u[r] = z[r] - lam*div(p)[r]  -- all rows independent
#pragma unroll
        for (int r = 0; r < TVR; r++) {
            int gi = gi0 + r;
            float pxm = __shfl_up(px_[r], 1);
            float divx = gj_le0 ? px_[r] : (gj_hi ? -pxm : px_[r] - pxm);
            float pym = (r > 0) ? py_[r - 1] : py_[0];   // r=0 is halo: don't-care
            float divy = (gi <= 0) ? py_[r]
                       : ((gi >= WID - 1) ? -pym : py_[r] - pym);
            u_[r] = z_[r] - LAM_TV * (divx + divy);
        }
        // pass 2: p[r] = proj(p[r] + tau*grad(u)[r]) -- all rows independent
#pragma unroll
        for (int r = 0; r < TVR; r++) {
            int gi = gi0 + r;
            float un = __shfl_down(u_[r], 1);
            float ub = (r < TVR - 1) ? u_[r + 1] : u_[r];  // last row halo: don't-care
            float gx = gx_on ? un - u_[r] : 0.f;
            float gy = (gi < WID - 1 && r < TVR - 1) ? ub - u_[r] : 0.f;
            float px = fmaf(0.25f, gx, px_[r]);
            float py = fmaf(0.25f, gy, py_[r]);
            float n2 = fmaf(px, px, fmaf(py, py, 1e-8f));
            float inv = fminf(rsqrtf(n2), 1.f);
            px_[r] = px * inv;
            py_[r] = py * inv;
        }
    }

    // final x_tv on interior rows -> uf[0..15]
    float uf[TIR];
#pragma unroll
    for (int r = 5; r < TVR - 5; r++) {
        int gi = gi0 + r;
        float pxm = __shfl_up(px_[r], 1);
        float divx = gj_le0 ? px_[r] : (gj_hi ? -pxm : px_[r] - pxm);
        float divy = (gi <= 0) ? py_[r]
                   : ((gi >= WID - 1) ? -py_[r - 1] : py_[r] - py_[r - 1]);
        uf[r - 5] = z_[r] - LAM_TV * (divx + divy);
    }

    // ---- 3-level Haar + soft-threshold (replicated-lane forward) ----
    const float sc1 = (lane & 1) ? -1.f : 1.f;
    const float sc2 = (lane & 2) ? -1.f : 1.f;
    const float sc3 = (lane & 4) ? -1.f : 1.f;

    float ll1[8], lh1[8], hl1[8], hh1[8];
#pragma unroll
    for (int k = 0; k < 8; k++) {
        float a0 = uf[2 * k], a1 = uf[2 * k + 1];
        float n0 = __shfl_xor(a0, 1), n1 = __shfl_xor(a1, 1);
        float h0 = a0 + n0, d0 = sc1 * (a0 - n0);   // (left-right) replicated
        float h1 = a1 + n1, d1 = sc1 * (a1 - n1);
        ll1[k] = (h0 + h1) * 0.5f;
        lh1[k] = softt((h0 - h1) * 0.5f);
        hl1[k] = softt((d0 + d1) * 0.5f);
        hh1[k] = softt((d0 - d1) * 0.5f);
    }
    float ll2[4], lh2[4], hl2[4], hh2[4];
#pragma unroll
    for (int k = 0; k < 4; k++) {
        float a0 = ll1[2 * k], a1 = ll1[2 * k + 1];
        float n0 = __shfl_xor(a0, 2), n1 = __shfl_xor(a1, 2);
        float h0 = a0 + n0, d0 = sc2 * (a0 - n0);
        float h1 = a1 + n1, d1 = sc2 * (a1 - n1);
        ll2[k] = (h0 + h1) * 0.5f;
        lh2[k] = softt((h0 - h1) * 0.5f);
        hl2[k] = softt((d0 + d1) * 0.5f);
        hh2[k] = softt((d0 - d1) * 0.5f);
    }
    float ll3[2], lh3[2], hl3[2], hh3[2];
#pragma unroll
    for (int k = 0; k < 2; k++) {
        float a0 = ll2[2 * k], a1 = ll2[2 * k + 1];
        float n0 = __shfl_xor(a0, 4), n1 = __shfl_xor(a1, 4);
        float h0 = a0 + n0, d0 = sc3 * (a0 - n0);
        float h1 = a1 + n1, d1 = sc3 * (a1 - n1);
        ll3[k] = (h0 + h1) * 0.5f;
        lh3[k] = softt((h0 - h1) * 0.5f);
        hl3[k] = softt((d0 + d1) * 0.5f);
        hh3[k] = softt((d0 - d1) * 0.5f);
    }
    // ---- inverse (shuffle-free: values replicated within blocks) ----
    float l2p[4];
#pragma unroll
    for (int k = 0; k < 2; k++) {
        l2p[2 * k]     = 0.5f * ((ll3[k] + lh3[k]) + sc3 * (hl3[k] + hh3[k]));
        l2p[2 * k + 1] = 0.5f * ((ll3[k] - lh3[k]) + sc3 * (hl3[k] - hh3[k]));
    }
    float l1p[8];
#pragma unroll
    for (int k = 0; k < 4; k++) {
        l1p[2 * k]     = 0.5f * ((l2p[k] + lh2[k]) + sc2 * (hl2[k] + hh2[k]));
        l1p[2 * k + 1] = 0.5f * ((l2p[k] - lh2[k]) + sc2 * (hl2[k] - hh2[k]));
    }
    float xn[TIR];
#pragma unroll
    for (int k = 0; k < 8; k++) {
        xn[2 * k]     = 0.5f * ((l1p[k] + lh1[k]) + sc1 * (hl1[k] + hh1[k]));
        xn[2 * k + 1] = 0.5f * ((l1p[k] - lh1[k]) + sc1 * (hl1[k] - hh1[k]));
    }

    // ---- FISTA: z = xn + beta*(xn - x_old); x = xn ----
    const bool wcol = (lane >= 8) && (lane < 56) && colin;
    float* px = x + (size_t)sl * HWc;
    float* pz = z + (size_t)sl * HWc;
    const int gi_int0 = trow * TIR;
#pragma unroll
    for (int i = 0; i < TIR; i++) {
        int off = (gi_int0 + i) * WID + gj;
        float xo = wcol ? px[off] : 0.f;
        float zn = xn[i] + beta * (xn[i] - xo);
        if (wcol) {
            px[off] = xn[i];
            pz[off] = zn;
        }
    }
}

// ---------------- host orchestration ----------------
extern "C" void kernel_launch(void* const* d_in, const int* in_sizes, int n_in,
                              void* d_out, int out_size, void* d_ws, size_t ws_size,
                              hipStream_t stream) {
    const float* y    = (const float*)d_in[0];
    const float* mask = (const float*)d_in[1];
    float* x = (float*)d_out;

    float* ws = (float*)d_ws;
    float* z  = ws;                       // NTOT
    float* t1 = ws + (size_t)NTOT;        // NTOT
    float* t2 = ws + 2 * (size_t)NTOT;    // NTOT

    const int ROW_BLKS = (NIMG * 320) / 4;   // 1280
    const int COL_BLKS = NIMG * 20;          // 320
    const int TV_BLKS  = (NSL * TPS) / 4;    // 1120

    // x0 = ifft2c(y): col-inverse then row-inverse (dual store -> x and z)
    fft_col<0><<<COL_BLKS, 256, 0, stream>>>(y, t1, nullptr, nullptr);
    fft_row<1, 3><<<ROW_BLKS, 256, 0, stream>>>(t1, x, nullptr, z);

    float t = 1.f;
    for (int it = 0; it < 15; it++) {
        // row-forward; fused (col-forward + DC + col-inverse); row-inverse
        // with residual epilogue: zs = z - g
        fft_row<-1, 0><<<ROW_BLKS, 256, 0, stream>>>(z, t1, nullptr, nullptr);
        fft_col<1><<<COL_BLKS, 256, 0, stream>>>(t1, t2, y, mask);
        fft_row<1, 2><<<ROW_BLKS, 256, 0, stream>>>(t2, t1, z, nullptr);

        // TV prox + wavelet shrinkage + FISTA momentum, one kernel
        float tn   = (1.f + sqrtf(1.f + 4.f * t * t)) * 0.5f;
        float beta = (t - 1.f) / tn;
        t = tn;
        tv_wav_fista<<<TV_BLKS, 256, 0, stream>>>(t1, x, z, beta);
    }
    (void)in_sizes; (void)n_in; (void)out_size; (void)ws_size;
}